// Round 9
// baseline (369.205 us; speedup 1.0000x reference)
//
#include <hip/hip_runtime.h>
#include <hip/hip_bf16.h>

#define B_ 4
#define N_ 2048
#define F_ 256
#define H_ 8
#define O_ 256

// log2(e)/16 folded into Q so softmax can use exp2f (exact softmax, monotone map)
#define SCALE_QK 0.09016844005556021f

typedef __attribute__((ext_vector_type(8))) short short8;
typedef __attribute__((ext_vector_type(4))) short s16x4;
typedef __attribute__((ext_vector_type(4))) float f32x4;
typedef __attribute__((ext_vector_type(4))) unsigned int u32x4;

static __device__ __forceinline__ float bf2f(short u) {
    unsigned int x = ((unsigned int)(unsigned short)u) << 16;
    return __builtin_bit_cast(float, x);
}
static __device__ __forceinline__ short f2bf(float f) {
    unsigned int x = __builtin_bit_cast(unsigned int, f);
    unsigned int lsb = (x >> 16) & 1u;
    x += 0x7fffu + lsb;
    return (short)(x >> 16);
}
static __device__ __forceinline__ unsigned int pkbf(float a, float b) {
    return (unsigned int)(unsigned short)f2bf(a) |
           ((unsigned int)(unsigned short)f2bf(b) << 16);
}

// async global->LDS 16B/lane; LDS dst is wave-uniform base + lane*16
static __device__ __forceinline__ void gld16(const short* g, short* l) {
    __builtin_amdgcn_global_load_lds(
        (const __attribute__((address_space(1))) void*)g,
        (__attribute__((address_space(3))) void*)l, 16, 0, 0);
}

// ---------------- f32 -> bf16 transpose: dst[c][r] = (bf16)src[r][c] ----
__global__ __launch_bounds__(256) void cvtT_kernel(const float* __restrict__ src,
                                                   short* __restrict__ dst,
                                                   int R, int C) {
    __shared__ short tile[32][33];
    src += (size_t)blockIdx.z * R * C;
    dst += (size_t)blockIdx.z * R * C;
    int tx = threadIdx.x, ty = threadIdx.y;           // 32 x 8
    int c0 = blockIdx.x * 32, r0 = blockIdx.y * 32;
#pragma unroll
    for (int j = 0; j < 4; j++) {
        int r = r0 + ty + j * 8;
        tile[ty + j * 8][tx] = f2bf(src[(size_t)r * C + c0 + tx]);
    }
    __syncthreads();
#pragma unroll
    for (int j = 0; j < 4; j++) {
        int c = c0 + ty + j * 8;
        dst[(size_t)c * R + r0 + tx] = tile[tx][ty + j * 8];
    }
}

// ---------------- f32 -> bf16 straight convert ----------------
__global__ __launch_bounds__(256) void cvt_kernel(const float* __restrict__ src,
                                                  short* __restrict__ dst, int n) {
    int i = blockIdx.x * 256 + threadIdx.x;
    if (n >= 2048) {
        size_t base = (size_t)i * 8;
#pragma unroll
        for (int j = 0; j < 8; j++) dst[base + j] = f2bf(src[base + j]);
    } else if (i < n) {
        dst[i] = f2bf(src[i]);
    }
}

// ---- 64-row MFMA GEMM tile, B^T input: C[m][n] = sum_k A[m][k]*Bt[n][k]
template <int NCT>
__device__ __forceinline__ void gemm64_bt(const short* __restrict__ A, int lda,
                                          const short* __restrict__ Bt, int ldb,
                                          float* __restrict__ C, int ldc,
                                          int K, const short* __restrict__ bias) {
    __shared__ short sA[64][72];
    __shared__ short sB[NCT * 16][72];
    int tid = threadIdx.x;
    int w = tid >> 6, l = tid & 63, lq = l & 15, quad = l >> 4;
    f32x4 acc[NCT];
#pragma unroll
    for (int i = 0; i < NCT; i++) acc[i] = (f32x4)(0.f);

    for (int kb = 0; kb < K; kb += 64) {
        __syncthreads();
#pragma unroll
        for (int i = 0; i < 2; i++) {
            int idx = tid + i * 256; int r = idx >> 3, c = (idx & 7) * 8;
            *(short8*)&sA[r][c] = *(const short8*)&A[(size_t)r * lda + kb + c];
        }
#pragma unroll
        for (int i = 0; i < NCT / 2; i++) {
            int idx = tid + i * 256; int r = idx >> 3, c = (idx & 7) * 8;
            *(short8*)&sB[r][c] = *(const short8*)&Bt[(size_t)r * ldb + kb + c];
        }
        __syncthreads();
#pragma unroll
        for (int kk = 0; kk < 2; kk++) {
            short8 af = *(const short8*)&sA[w * 16 + lq][kk * 32 + quad * 8];
#pragma unroll
            for (int ct = 0; ct < NCT; ct++) {
                short8 bf = *(const short8*)&sB[ct * 16 + lq][kk * 32 + quad * 8];
                acc[ct] = __builtin_amdgcn_mfma_f32_16x16x32_bf16(af, bf, acc[ct], 0, 0, 0);
            }
        }
    }
#pragma unroll
    for (int ct = 0; ct < NCT; ct++) {
        int col = ct * 16 + lq;
        float bv = bias ? bf2f(bias[col]) : 0.f;
#pragma unroll
        for (int r = 0; r < 4; r++) {
            int row = w * 16 + quad * 4 + r;
            C[(size_t)row * ldc + col] = acc[ct][r] + bv;
        }
    }
}

// out[m][o] = msgs[m][:] @ Wout + bias; grid (128,4) = 512 blocks -> 2/CU
__global__ __launch_bounds__(256) void out_kernel(const short* __restrict__ msgs,
                                                  const short* __restrict__ WoutT,
                                                  const short* __restrict__ bias,
                                                  float* __restrict__ out) {
    int mt = blockIdx.x, nt = blockIdx.y;
    gemm64_bt<4>(msgs + (size_t)mt * 64 * (H_ * F_), H_ * F_,
                 WoutT + (size_t)nt * 64 * (H_ * F_), H_ * F_,
                 out + (size_t)mt * 64 * O_ + nt * 64, O_,
                 H_ * F_, bias + nt * 64);
}

// ============ fused flash attention, double-buffered, 32 q/wave ============
// Block: 256 threads = 4 waves, 128 q. Wave w owns q = q0 + m*64 + w*16 + lq
// for m in {0,1}. BN=64 keys/iter. S^T = K·Q^T (A = keys from LDS, shared
// across both m; B = Q regs); O^T = V^T·P^T (A = V^T from LDS, shared across
// both m; B = P^T via register shuffles). Every LDS a-frag read feeds 2 MFMAs.
// Two static LDS buffer pairs, one barrier per kt. LDS = 128 KB -> 1 block/CU,
// 1 wave/SIMD, VGPR cap 512 (no spill possible).

// stage key-tile KT: K rows into KVF [64][256] (XOR b^(r&31)),
// V^T rows into KVTF [256][64] (XOR b^(r&7)); 4 waves, 16 gld16/lane.
#define STAGE_KV(KT, KVF, KVTF) do {                                         \
    _Pragma("unroll")                                                        \
    for (int i_ = 0; i_ < 8; i_++) {                                         \
        int rk_ = w * 16 + i_ * 2 + (l >> 5);                                \
        int bk_ = (l & 31) ^ (rk_ & 31);                                     \
        gld16(&Xb[(size_t)((KT) * 64 + rk_) * F_ + bk_ * 8],                 \
              &KVF[(w * 16 + i_ * 2) * 256]);                                \
        int rt_ = w * 64 + i_ * 8 + (l >> 3);                                \
        int bt_ = (l & 7) ^ (rt_ & 7);                                       \
        gld16(&XTb[(size_t)rt_ * N_ + (KT) * 64 + bt_ * 8],                  \
              &KVTF[(w * 64 + i_ * 8) * 64]);                                \
    }                                                                        \
} while (0)

#define COMPUTE_KT(KVF, KVTF) do {                                           \
    f32x4 sacc[2][4];                                                        \
    _Pragma("unroll")                                                        \
    for (int m_ = 0; m_ < 2; m_++)                                           \
        _Pragma("unroll")                                                    \
        for (int ct = 0; ct < 4; ct++) sacc[m_][ct] = (f32x4)(0.f);          \
    _Pragma("unroll")                                                        \
    for (int kk = 0; kk < 8; kk++) {                                         \
        _Pragma("unroll")                                                    \
        for (int ct = 0; ct < 4; ct++) {                                     \
            int arow = ct * 16 + lq;                                         \
            int ab = (kk * 4 + quad) ^ (arow & 31);                          \
            short8 af = *(const short8*)&KVF[arow * 256 + ab * 8];           \
            sacc[0][ct] = __builtin_amdgcn_mfma_f32_16x16x32_bf16(af, aq[0][kk], sacc[0][ct], 0, 0, 0); \
            sacc[1][ct] = __builtin_amdgcn_mfma_f32_16x16x32_bf16(af, aq[1][kk], sacc[1][ct], 0, 0, 0); \
        }                                                                    \
    }                                                                        \
    float alpha[2];                                                          \
    short8 pfrag[2][2];                                                      \
    _Pragma("unroll")                                                        \
    for (int m_ = 0; m_ < 2; m_++) {                                         \
        float mx = -INFINITY;                                                \
        _Pragma("unroll")                                                    \
        for (int ct = 0; ct < 4; ct++)                                       \
            _Pragma("unroll")                                                \
            for (int r_ = 0; r_ < 4; r_++) mx = fmaxf(mx, sacc[m_][ct][r_]); \
        mx = fmaxf(mx, __shfl_xor(mx, 16));                                  \
        mx = fmaxf(mx, __shfl_xor(mx, 32));                                  \
        float mn = fmaxf(m_q[m_], mx);                                       \
        alpha[m_] = exp2f(m_q[m_] - mn);                                     \
        m_q[m_] = mn;                                                        \
        float pv[4][4]; float s_ = 0.f;                                      \
        _Pragma("unroll")                                                    \
        for (int ct = 0; ct < 4; ct++)                                       \
            _Pragma("unroll")                                                \
            for (int r_ = 0; r_ < 4; r_++) {                                 \
                pv[ct][r_] = exp2f(sacc[m_][ct][r_] - mn);                   \
                s_ += pv[ct][r_];                                            \
            }                                                                \
        s_ += __shfl_xor(s_, 16);                                            \
        s_ += __shfl_xor(s_, 32);                                            \
        l_q[m_] = l_q[m_] * alpha[m_] + s_;                                  \
        unsigned int w2[4][2];                                               \
        _Pragma("unroll")                                                    \
        for (int ct = 0; ct < 4; ct++) {                                     \
            w2[ct][0] = pkbf(pv[ct][0], pv[ct][1]);                          \
            w2[ct][1] = pkbf(pv[ct][2], pv[ct][3]);                          \
        }                                                                    \
        int sl0 = (2 * (quad & 1)) * 16 + lq;                                \
        int sl1 = sl0 + 16;                                                  \
        bool hi = (quad >> 1) != 0;                                          \
        _Pragma("unroll")                                                    \
        for (int kk = 0; kk < 2; kk++) {                                     \
            unsigned int u0 = __shfl((int)w2[2 * kk][0], sl0);               \
            unsigned int u1 = __shfl((int)w2[2 * kk][1], sl0);               \
            unsigned int u2 = __shfl((int)w2[2 * kk][0], sl1);               \
            unsigned int u3 = __shfl((int)w2[2 * kk][1], sl1);               \
            unsigned int v0 = __shfl((int)w2[2 * kk + 1][0], sl0);           \
            unsigned int v1 = __shfl((int)w2[2 * kk + 1][1], sl0);           \
            unsigned int v2 = __shfl((int)w2[2 * kk + 1][0], sl1);           \
            unsigned int v3 = __shfl((int)w2[2 * kk + 1][1], sl1);           \
            u32x4 pk = { hi ? v0 : u0, hi ? v1 : u1, hi ? v2 : u2, hi ? v3 : u3 }; \
            pfrag[m_][kk] = __builtin_bit_cast(short8, pk);                  \
        }                                                                    \
    }                                                                        \
    if (!__all(alpha[0] == 1.0f && alpha[1] == 1.0f)) {                      \
        _Pragma("unroll")                                                    \
        for (int m_ = 0; m_ < 2; m_++)                                       \
            _Pragma("unroll")                                                \
            for (int ct = 0; ct < 16; ct++)                                  \
                _Pragma("unroll")                                            \
                for (int r_ = 0; r_ < 4; r_++) oacc[m_][ct][r_] *= alpha[m_]; \
    }                                                                        \
    _Pragma("unroll")                                                        \
    for (int ct = 0; ct < 16; ct++) {                                        \
        int arow = ct * 16 + lq;                                             \
        short8 a0 = *(const short8*)&KVTF[arow * 64 + ((quad) ^ (arow & 7)) * 8]; \
        short8 a1 = *(const short8*)&KVTF[arow * 64 + ((4 + quad) ^ (arow & 7)) * 8]; \
        oacc[0][ct] = __builtin_amdgcn_mfma_f32_16x16x32_bf16(a0, pfrag[0][0], oacc[0][ct], 0, 0, 0); \
        oacc[0][ct] = __builtin_amdgcn_mfma_f32_16x16x32_bf16(a1, pfrag[0][1], oacc[0][ct], 0, 0, 0); \
        oacc[1][ct] = __builtin_amdgcn_mfma_f32_16x16x32_bf16(a0, pfrag[1][0], oacc[1][ct], 0, 0, 0); \
        oacc[1][ct] = __builtin_amdgcn_mfma_f32_16x16x32_bf16(a1, pfrag[1][1], oacc[1][ct], 0, 0, 0); \
    }                                                                        \
} while (0)

__global__ __launch_bounds__(256) void attn_kernel(const short* __restrict__ X,
                                                   const short* __restrict__ WhT,
                                                   const short* __restrict__ XT,
                                                   short* __restrict__ msgs) {
    __shared__ short kvfA[64 * 256];    // 32 KB
    __shared__ short kvfB[64 * 256];    // 32 KB
    __shared__ short kvTfA[256 * 64];   // 32 KB
    __shared__ short kvTfB[256 * 64];   // 32 KB

    int qt = blockIdx.x, bh = blockIdx.y, b = bh >> 3, h = bh & 7;
    int tid = threadIdx.x, w = tid >> 6, l = tid & 63, lq = l & 15, quad = l >> 4;
    int q0 = qt * 128;

    const short* Xb  = X  + (size_t)b * N_ * F_;
    const short* XTb = XT + (size_t)b * F_ * N_;
    const short* Whh = WhT + (size_t)h * F_ * F_;

    f32x4 oacc[2][16];
    short8 aq[2][8];

    // ---------- phase 0: Q = (X qtile @ Wh) * SCALE_QK (128 q rows) ----------
#pragma unroll
    for (int m = 0; m < 2; m++)
#pragma unroll
        for (int i = 0; i < 16; i++) oacc[m][i] = (f32x4)(0.f);
    // stage X rows: q0..q0+63 -> kvfA, q0+64..q0+127 -> kvfB (each wave 2x16 rows)
#pragma unroll
    for (int i = 0; i < 8; i++) {
        int r = w * 16 + i * 2 + (l >> 5);
        int bb = (l & 31) ^ (r & 31);
        gld16(&Xb[(size_t)(q0 + r) * F_ + bb * 8],       &kvfA[(w * 16 + i * 2) * 256]);
        gld16(&Xb[(size_t)(q0 + 64 + r) * F_ + bb * 8],  &kvfB[(w * 16 + i * 2) * 256]);
    }
#pragma unroll 1
    for (int kb = 0; kb < 4; kb++) {
        __syncthreads();   // prev kb's W reads done
#pragma unroll
        for (int i = 0; i < 8; i++) {   // stage WhT[h][0:256][kb*64..+63] -> kvTfA
            int rt = w * 64 + i * 8 + (l >> 3);
            int bt = (l & 7) ^ (rt & 7);
            gld16(&Whh[(size_t)rt * F_ + kb * 64 + bt * 8], &kvTfA[(w * 64 + i * 8) * 64]);
        }
        __syncthreads();   // drains DMA (X on kb==0, W always)
#pragma unroll
        for (int kk = 0; kk < 2; kk++) {
            int arow = w * 16 + lq;
            int ab = (kb * 8 + kk * 4 + quad) ^ (arow & 31);
            short8 af0 = *(const short8*)&kvfA[arow * 256 + ab * 8];
            short8 af1 = *(const short8*)&kvfB[arow * 256 + ab * 8];
#pragma unroll
            for (int ct = 0; ct < 16; ct++) {
                int brow = ct * 16 + lq;
                int bb = (kk * 4 + quad) ^ (brow & 7);
                short8 bf = *(const short8*)&kvTfA[brow * 64 + bb * 8];
                oacc[0][ct] = __builtin_amdgcn_mfma_f32_16x16x32_bf16(af0, bf, oacc[0][ct], 0, 0, 0);
                oacc[1][ct] = __builtin_amdgcn_mfma_f32_16x16x32_bf16(af1, bf, oacc[1][ct], 0, 0, 0);
            }
        }
    }
    __syncthreads();   // all W/X reads done; reuse kvTfA/B as Q [64 q][256 f], XOR b^(r&31)
#pragma unroll
    for (int ct = 0; ct < 16; ct++) {
#pragma unroll
        for (int r = 0; r < 4; r++) {
            int row = w * 16 + quad * 4 + r;
            int col = ct * 16 + lq;
            int pb = (col >> 3) ^ (row & 31);
            kvTfA[row * 256 + pb * 8 + (col & 7)] = f2bf(oacc[0][ct][r] * SCALE_QK);
            kvTfB[row * 256 + pb * 8 + (col & 7)] = f2bf(oacc[1][ct][r] * SCALE_QK);
        }
    }
    __syncthreads();
#pragma unroll
    for (int kk = 0; kk < 8; kk++) {   // aq[m]: B-frag Q[q=w*16+lq][kk*32+quad*8..]
        int row = w * 16 + lq;
        int ab = (kk * 4 + quad) ^ (row & 31);
        aq[0][kk] = *(const short8*)&kvTfA[row * 256 + ab * 8];
        aq[1][kk] = *(const short8*)&kvTfB[row * 256 + ab * 8];
    }
    __syncthreads();   // all aq reads done before tile-0 DMA overwrites kvTfA

    // ---------- phase 1: pipelined flash attention ----------
#pragma unroll
    for (int m = 0; m < 2; m++)
#pragma unroll
        for (int i = 0; i < 16; i++) oacc[m][i] = (f32x4)(0.f);
    float m_q[2] = {-INFINITY, -INFINITY};   // q = q0 + m*64 + w*16 + lq
    float l_q[2] = {0.f, 0.f};

    STAGE_KV(0, kvfA, kvTfA);
    __syncthreads();   // drain tile-0 DMA

#pragma unroll 1
    for (int kt2 = 0; kt2 < 16; kt2++) {
        // half A: prefetch tile 2*kt2+1 -> B pair, compute from A pair
        STAGE_KV(2 * kt2 + 1, kvfB, kvTfB);
        COMPUTE_KT(kvfA, kvTfA);
        __syncthreads();   // all A-reads done + B-prefetch (issued pre-compute) drained
        // half B: prefetch tile (2*kt2+2)&31 -> A pair, compute from B pair
        STAGE_KV((2 * kt2 + 2) & 31, kvfA, kvTfA);   // last iter refetches tile 0 (unused)
        COMPUTE_KT(kvfB, kvTfB);
        __syncthreads();
    }

    // epilogue: per-lane q = q0 + m*64 + w*16 + lq; feats ct*16 + quad*4 + r
#pragma unroll
    for (int m = 0; m < 2; m++) {
        float inv = 1.f / l_q[m];
        short* Mout = msgs + (size_t)(b * N_ + q0 + m * 64 + w * 16 + lq) * (H_ * F_) + h * F_;
#pragma unroll
        for (int ct = 0; ct < 16; ct++) {
            s16x4 v4 = { f2bf(oacc[m][ct][0] * inv), f2bf(oacc[m][ct][1] * inv),
                         f2bf(oacc[m][ct][2] * inv), f2bf(oacc[m][ct][3] * inv) };
            *(s16x4*)&Mout[ct * 16 + quad * 4] = v4;
        }
    }
}

extern "C" void kernel_launch(void* const* d_in, const int* in_sizes, int n_in,
                              void* d_out, int out_size, void* d_ws, size_t ws_size,
                              hipStream_t stream) {
    const float* nodes = (const float*)d_in[0];   // [4,2048,256] f32
    const float* Wh    = (const float*)d_in[1];   // [8,256,256]  f32
    const float* Wout  = (const float*)d_in[2];   // [2048,256]   f32
    const float* bias  = (const float*)d_in[3];   // [256]        f32
    float* out = (float*)d_out;                   // [4,2048,256] f32

    char* ws = (char*)d_ws;
    short* msgs   = (short*)(ws);                   // [8192][2048] bf16 = 32 MB
    short* WhT    = (short*)(ws + 33554432);        // [8][256][256]       1 MB
    short* WoutT  = (short*)(ws + 34603008);        // [256][2048]         1 MB
    short* XT     = (short*)(ws + 35651584);        // [4][256][2048]      4 MB
    short* Xbf    = (short*)(ws + 39845888);        // [4][2048][256]      4 MB
    short* biasbf = (short*)(ws + 44040192);        // [256]

    dim3 tblk(32, 8, 1);
    hipLaunchKernelGGL(cvtT_kernel, dim3(8, 8, 8),  tblk, 0, stream, Wh,    WhT,   256,  256);
    hipLaunchKernelGGL(cvtT_kernel, dim3(8, 64, 1), tblk, 0, stream, Wout,  WoutT, 2048, 256);
    hipLaunchKernelGGL(cvtT_kernel, dim3(8, 64, 4), tblk, 0, stream, nodes, XT,    2048, 256);
    hipLaunchKernelGGL(cvt_kernel,  dim3(1024), dim3(256), 0, stream, nodes, Xbf, 2097152);
    hipLaunchKernelGGL(cvt_kernel,  dim3(1),    dim3(256), 0, stream, bias, biasbf, 256);

    hipLaunchKernelGGL(attn_kernel, dim3(16, 32), dim3(256), 0, stream, Xbf, WhT, XT, msgs);
    hipLaunchKernelGGL(out_kernel,  dim3(128, 4), dim3(256), 0, stream, msgs, WoutT, biasbf, out);
}